// Round 2
// baseline (230.865 us; speedup 1.0000x reference)
//
#include <hip/hip_runtime.h>
#include <hip/hip_bf16.h>
#include <stdint.h>

#define BATCH 2
#define SEQ   2048
#define DIM   1024
#define NH    16
#define HD    64
#define MVAL  (-10000.0f)

typedef __attribute__((ext_vector_type(8))) short bf16x8;
typedef __attribute__((ext_vector_type(4))) float f32x4;
typedef unsigned short u16;

static __device__ __forceinline__ u16 f2bf(float f) {
  union { float f; uint32_t u; } c; c.f = f;
  uint32_t x = c.u;
  return (u16)((x + 0x7fffu + ((x >> 16) & 1u)) >> 16);  // RNE
}

// swizzled byte offset within LDS tiles of 128B rows (8 x 16B chunks)
static __device__ __forceinline__ int swz128(int row, int chunk) {
  return row * 128 + (((chunk ^ (row & 7)) & 7) << 4);
}

static __device__ __forceinline__ void gload_lds16(const void* g, void* l) {
  __builtin_amdgcn_global_load_lds((const __attribute__((address_space(1))) void*)g,
                                   (__attribute__((address_space(3))) void*)l, 16, 0, 0);
}

// ---------------- fp32 -> bf16 convert (vectorized) ----------------
__global__ void cvt_kernel(const float* __restrict__ in, u16* __restrict__ out, int n4) {
  int i = blockIdx.x * blockDim.x + threadIdx.x;
  if (i < n4) {
    float4 v = reinterpret_cast<const float4*>(in)[i];
    uint32_t p0 = (uint32_t)f2bf(v.x) | ((uint32_t)f2bf(v.y) << 16);
    uint32_t p1 = (uint32_t)f2bf(v.z) | ((uint32_t)f2bf(v.w) << 16);
    reinterpret_cast<uint2*>(out)[i] = make_uint2(p0, p1);
  }
}

// -------- fp32 [R][C] -> bf16 [C][R] transpose via LDS tile --------
__global__ void transpose_cvt_kernel(const float* __restrict__ in, u16* __restrict__ out,
                                     int R, int C) {
  __shared__ float tile[32][33];
  int c0 = blockIdx.x * 32, r0 = blockIdx.y * 32;
  int tx = threadIdx.x, ty = threadIdx.y;
#pragma unroll
  for (int i = 0; i < 32; i += 8)
    tile[ty + i][tx] = in[(size_t)(r0 + ty + i) * C + c0 + tx];
  __syncthreads();
#pragma unroll
  for (int i = 0; i < 32; i += 8)
    out[(size_t)(c0 + ty + i) * R + r0 + tx] = f2bf(tile[tx][ty + i]);
}

// ---------------- bf16 GEMM: C = A[M,K] * Bt[N,K]^T + bias ----------------
// global_load_lds(16B) staging, LINEAR LDS (m97 structure).
// EPI==0: scatter to Q/K head-split [bh][s][d] (Q pre-scaled by 0.125) and
//         V transposed [bh][d][s] (bf16)
// EPI==1: plain fp32 [M][N] output
template <int EPI>
__global__ __launch_bounds__(256, 2) void gemm_bt_kernel(
    const u16* __restrict__ A, const u16* __restrict__ Bt,
    const float* __restrict__ bias, float* __restrict__ Cout,
    u16* __restrict__ Qo, u16* __restrict__ Ko, u16* __restrict__ Vto,
    int M, int N, int K) {
  __shared__ __align__(16) char lds[32768];
  char* As = lds;            // 128 rows x 64 bf16, linear 128B rows
  char* Bs = lds + 16384;
  int tid = threadIdx.x;
  int lane = tid & 63, l15 = lane & 15, l4 = lane >> 4;
  int w = tid >> 6, wr = w >> 1, wc = w & 1;
  int m0 = blockIdx.y * 128, n0 = blockIdx.x * 128;
  int srow = tid >> 3, sch = tid & 7;

  const u16* Ap = A + (size_t)(m0 + srow) * K + sch * 8;
  const u16* Bp = Bt + (size_t)(n0 + srow) * K + sch * 8;

  f32x4 acc[4][4] = {};

  for (int k0 = 0; k0 < K; k0 += 64) {
    __syncthreads();
#pragma unroll
    for (int i = 0; i < 4; i++) {
      gload_lds16(Ap + (size_t)i * 32 * K + k0, As + i * 4096 + tid * 16);
      gload_lds16(Bp + (size_t)i * 32 * K + k0, Bs + i * 4096 + tid * 16);
    }
    __syncthreads();
#pragma unroll
    for (int ks = 0; ks < 2; ks++) {
      int ch = ks * 4 + l4;
      bf16x8 af[4], bfv[4];
#pragma unroll
      for (int mi = 0; mi < 4; mi++)
        af[mi] = *reinterpret_cast<const bf16x8*>(As + (wr * 64 + mi * 16 + l15) * 128 + ch * 16);
#pragma unroll
      for (int nj = 0; nj < 4; nj++)
        bfv[nj] = *reinterpret_cast<const bf16x8*>(Bs + (wc * 64 + nj * 16 + l15) * 128 + ch * 16);
#pragma unroll
      for (int mi = 0; mi < 4; mi++)
#pragma unroll
        for (int nj = 0; nj < 4; nj++)
          acc[mi][nj] = __builtin_amdgcn_mfma_f32_16x16x32_bf16(af[mi], bfv[nj], acc[mi][nj], 0, 0, 0);
    }
  }

#pragma unroll
  for (int nj = 0; nj < 4; nj++) {
    int n = n0 + wc * 64 + nj * 16 + l15;
    float bv = bias[n];
#pragma unroll
    for (int mi = 0; mi < 4; mi++) {
#pragma unroll
      for (int r = 0; r < 4; r++) {
        int m = m0 + wr * 64 + mi * 16 + l4 * 4 + r;
        float v = acc[mi][nj][r] + bv;
        if (EPI == 1) {
          Cout[(size_t)m * N + n] = v;
        } else {
          int b = m >> 11, s = m & 2047;
          int sec = n >> 10, c = n & 1023, h = c >> 6, d = c & 63;
          size_t bh = (size_t)(b * NH + h);
          if (sec == 0)      Qo[(bh * SEQ + s) * HD + d] = f2bf(v * 0.125f);  // fold softmax scale
          else if (sec == 1) Ko[(bh * SEQ + s) * HD + d] = f2bf(v);
          else               Vto[(bh * HD + d) * SEQ + s] = f2bf(v);
        }
      }
    }
  }
}

// ---------------- causal flash attention, wave-independent ----------------
// 2048 independent waves; wave = one (bh, 32-q-row chunk). No barriers.
// K/V fragments read directly from global (L2-resident per head).
// grid: 512 blocks x 256 threads (4 waves)
__global__ __launch_bounds__(256) void attn_kernel(
    const u16* __restrict__ Q, const u16* __restrict__ K,
    const u16* __restrict__ Vt, u16* __restrict__ O) {
  __shared__ __align__(16) char lds[16384];   // 4 waves x 4KB P scratch
  int tid = threadIdx.x, lane = tid & 63, w = tid >> 6;
  int l15 = lane & 15, l4 = lane >> 4;
  int item = blockIdx.x * 4 + w;
  int bh = item >> 6, qt = item & 63;
  int qbase = qt * 32;
  const u16* Qh = Q + (size_t)bh * SEQ * HD;
  const u16* Kh = K + (size_t)bh * SEQ * HD;
  const u16* Vh = Vt + (size_t)bh * HD * SEQ;
  char* Pw = lds + w * 4096;

  // Q fragments (pre-scaled by 0.125 in gemm epilogue): [mi][ks]
  bf16x8 qf[2][2];
#pragma unroll
  for (int mi = 0; mi < 2; mi++)
#pragma unroll
    for (int ks = 0; ks < 2; ks++)
      qf[mi][ks] = *reinterpret_cast<const bf16x8*>(
          Qh + (size_t)(qbase + mi * 16 + l15) * HD + ks * 32 + l4 * 8);

  float mrun[2][4], lrun[2][4];
  f32x4 oacc[2][4] = {};
#pragma unroll
  for (int mi = 0; mi < 2; mi++)
#pragma unroll
    for (int r = 0; r < 4; r++) { mrun[mi][r] = -1e30f; lrun[mi][r] = 0.0f; }

  int nkt = (qt + 2) >> 1;  // 64-wide kv tiles covering [0, qbase+32)

  for (int kt = 0; kt < nkt; kt++) {
    const u16* Kt = Kh + (size_t)kt * 64 * HD;
    // K fragments [nj][ks] direct from global
    bf16x8 kf[4][2];
#pragma unroll
    for (int nj = 0; nj < 4; nj++)
#pragma unroll
      for (int ks = 0; ks < 2; ks++)
        kf[nj][ks] = *reinterpret_cast<const bf16x8*>(
            Kt + (size_t)(nj * 16 + l15) * HD + ks * 32 + l4 * 8);
    // V fragments [nd][ks] direct from global (issued early; consumed in PV)
    bf16x8 vf[4][2];
#pragma unroll
    for (int nd = 0; nd < 4; nd++)
#pragma unroll
      for (int ks = 0; ks < 2; ks++)
        vf[nd][ks] = *reinterpret_cast<const bf16x8*>(
            Vh + (size_t)(nd * 16 + l15) * SEQ + kt * 64 + ks * 32 + l4 * 8);

    // S = Q K^T (pre-scaled)
    f32x4 s[2][4] = {};
#pragma unroll
    for (int ks = 0; ks < 2; ks++)
#pragma unroll
      for (int nj = 0; nj < 4; nj++)
#pragma unroll
        for (int mi = 0; mi < 2; mi++)
          s[mi][nj] = __builtin_amdgcn_mfma_f32_16x16x32_bf16(qf[mi][ks], kf[nj][ks], s[mi][nj], 0, 0, 0);

    // causal mask (only on diagonal-overlapping tiles) + tile row-max
    float mt[2][4];
#pragma unroll
    for (int mi = 0; mi < 2; mi++)
#pragma unroll
      for (int r = 0; r < 4; r++) mt[mi][r] = -1e30f;
    if (kt * 64 + 63 <= qbase) {
#pragma unroll
      for (int mi = 0; mi < 2; mi++)
#pragma unroll
        for (int nj = 0; nj < 4; nj++)
#pragma unroll
          for (int r = 0; r < 4; r++)
            mt[mi][r] = fmaxf(mt[mi][r], s[mi][nj][r]);
    } else {
#pragma unroll
      for (int mi = 0; mi < 2; mi++)
#pragma unroll
        for (int nj = 0; nj < 4; nj++)
#pragma unroll
          for (int r = 0; r < 4; r++) {
            int qg = qbase + mi * 16 + l4 * 4 + r;
            int kg = kt * 64 + nj * 16 + l15;
            float v = (kg <= qg) ? s[mi][nj][r] : MVAL;
            s[mi][nj][r] = v;
            mt[mi][r] = fmaxf(mt[mi][r], v);
          }
    }
#pragma unroll
    for (int mi = 0; mi < 2; mi++)
#pragma unroll
      for (int r = 0; r < 4; r++) {
        float v = mt[mi][r];
        v = fmaxf(v, __shfl_xor(v, 1));
        v = fmaxf(v, __shfl_xor(v, 2));
        v = fmaxf(v, __shfl_xor(v, 4));
        v = fmaxf(v, __shfl_xor(v, 8));
        mt[mi][r] = v;
      }

    // online-softmax update
    float alpha[2][4];
#pragma unroll
    for (int mi = 0; mi < 2; mi++)
#pragma unroll
      for (int r = 0; r < 4; r++) {
        float mnew = fmaxf(mrun[mi][r], mt[mi][r]);
        alpha[mi][r] = __expf(mrun[mi][r] - mnew);
        mrun[mi][r] = mnew;
#pragma unroll
        for (int nd = 0; nd < 4; nd++) oacc[mi][nd][r] *= alpha[mi][r];
      }

    // P = exp(S - m) -> bf16 P in per-wave LDS; accumulate row sums
    float rs[2][4] = {};
#pragma unroll
    for (int mi = 0; mi < 2; mi++)
#pragma unroll
      for (int nj = 0; nj < 4; nj++)
#pragma unroll
        for (int r = 0; r < 4; r++) {
          float p = __expf(s[mi][nj][r] - mrun[mi][r]);
          rs[mi][r] += p;
          int row = mi * 16 + l4 * 4 + r;
          int col = nj * 16 + l15;
          *reinterpret_cast<u16*>(Pw + row * 128 + ((((col >> 3) ^ (row & 7)) & 7) << 4) +
                                  (col & 7) * 2) = f2bf(p);
        }
#pragma unroll
    for (int mi = 0; mi < 2; mi++)
#pragma unroll
      for (int r = 0; r < 4; r++) {
        float v = rs[mi][r];
        v += __shfl_xor(v, 1);
        v += __shfl_xor(v, 2);
        v += __shfl_xor(v, 4);
        v += __shfl_xor(v, 8);
        lrun[mi][r] = lrun[mi][r] * alpha[mi][r] + v;
      }

    asm volatile("s_waitcnt lgkmcnt(0)" ::: "memory");
    __builtin_amdgcn_sched_barrier(0);

    // O += P V
#pragma unroll
    for (int ks = 0; ks < 2; ks++) {
      int ch = ks * 4 + l4;
      bf16x8 pf[2];
#pragma unroll
      for (int mi = 0; mi < 2; mi++)
        pf[mi] = *reinterpret_cast<const bf16x8*>(Pw + swz128(mi * 16 + l15, ch));
#pragma unroll
      for (int nd = 0; nd < 4; nd++)
#pragma unroll
        for (int mi = 0; mi < 2; mi++)
          oacc[mi][nd] = __builtin_amdgcn_mfma_f32_16x16x32_bf16(pf[mi], vf[nd][ks], oacc[mi][nd], 0, 0, 0);
    }
  }

  // write O merged-heads [B][S][D] bf16
  int b = bh >> 4, h = bh & 15;
  float inv[2][4];
#pragma unroll
  for (int mi = 0; mi < 2; mi++)
#pragma unroll
    for (int r = 0; r < 4; r++) inv[mi][r] = 1.0f / lrun[mi][r];
#pragma unroll
  for (int mi = 0; mi < 2; mi++)
#pragma unroll
    for (int nd = 0; nd < 4; nd++)
#pragma unroll
      for (int r = 0; r < 4; r++) {
        int qrow = qbase + mi * 16 + l4 * 4 + r;
        int d = nd * 16 + l15;
        O[((size_t)b * SEQ + qrow) * DIM + h * HD + d] = f2bf(oacc[mi][nd][r] * inv[mi][r]);
      }
}

extern "C" void kernel_launch(void* const* d_in, const int* in_sizes, int n_in,
                              void* d_out, int out_size, void* d_ws, size_t ws_size,
                              hipStream_t stream) {
  const float* x     = (const float*)d_in[0];
  const float* W_qkv = (const float*)d_in[1];
  const float* b_qkv = (const float*)d_in[2];
  const float* W_out = (const float*)d_in[3];
  const float* b_out = (const float*)d_in[4];
  float* out = (float*)d_out;
  char* ws = (char*)d_ws;

  // ws layout (bytes)
  u16* xb    = (u16*)(ws);                               // 8 MB  [4096][1024]
  u16* WqkvT = (u16*)(ws + 8388608);                     // 6 MB  [3072][1024]
  u16* WoutT = (u16*)(ws + 8388608 + 6291456);           // 2 MB  [1024][1024]
  u16* Qb    = (u16*)(ws + 16777216);                    // 8 MB  [32][2048][64]
  u16* Kb    = (u16*)(ws + 16777216 + 8388608);          // 8 MB  [32][2048][64]
  u16* Vtb   = (u16*)(ws + 16777216 + 2 * 8388608);      // 8 MB  [32][64][2048]
  u16* Ob    = (u16*)(ws + 16777216 + 3 * 8388608);      // 8 MB  [4096][1024]

  cvt_kernel<<<4096, 256, 0, stream>>>(x, xb, BATCH * SEQ * DIM / 4);
  transpose_cvt_kernel<<<dim3(3 * DIM / 32, DIM / 32), dim3(32, 8), 0, stream>>>(
      W_qkv, WqkvT, DIM, 3 * DIM);
  transpose_cvt_kernel<<<dim3(DIM / 32, DIM / 32), dim3(32, 8), 0, stream>>>(
      W_out, WoutT, DIM, DIM);
  gemm_bt_kernel<0><<<dim3(3 * DIM / 128, BATCH * SEQ / 128), 256, 0, stream>>>(
      xb, WqkvT, b_qkv, nullptr, Qb, Kb, Vtb, BATCH * SEQ, 3 * DIM, DIM);
  attn_kernel<<<512, 256, 0, stream>>>(Qb, Kb, Vtb, Ob);
  gemm_bt_kernel<1><<<dim3(DIM / 128, BATCH * SEQ / 128), 256, 0, stream>>>(
      Ob, WoutT, b_out, out, nullptr, nullptr, nullptr, BATCH * SEQ, DIM, DIM);
}

// Round 3
// 149.796 us; speedup vs baseline: 1.5412x; 1.5412x over previous
//
#include <hip/hip_runtime.h>
#include <hip/hip_bf16.h>
#include <stdint.h>

#define BATCH 2
#define SEQ   2048
#define DIM   1024
#define NH    16
#define HD    64
#define MVAL  (-10000.0f)

typedef __attribute__((ext_vector_type(8))) short bf16x8;
typedef __attribute__((ext_vector_type(4))) float f32x4;
typedef unsigned short u16;

static __device__ __forceinline__ u16 f2bf(float f) {
  union { float f; uint32_t u; } c; c.f = f;
  uint32_t x = c.u;
  return (u16)((x + 0x7fffu + ((x >> 16) & 1u)) >> 16);  // RNE
}

static __device__ __forceinline__ uint32_t pk2(float a, float b) {
  __hip_bfloat162 h = __float22bfloat162_rn(make_float2(a, b));
  union { __hip_bfloat162 h; uint32_t u; } c; c.h = h;
  return c.u;
}

// swizzled byte offset within LDS tiles of 128B rows (8 x 16B chunks)
static __device__ __forceinline__ int swz128(int row, int chunk) {
  return row * 128 + (((chunk ^ (row & 7)) & 7) << 4);
}

static __device__ __forceinline__ void gload_lds16(const void* g, void* l) {
  __builtin_amdgcn_global_load_lds((const __attribute__((address_space(1))) void*)g,
                                   (__attribute__((address_space(3))) void*)l, 16, 0, 0);
}

// ---------------- fp32 -> bf16 convert (vectorized) ----------------
__global__ void cvt_kernel(const float* __restrict__ in, u16* __restrict__ out, int n4) {
  int i = blockIdx.x * blockDim.x + threadIdx.x;
  if (i < n4) {
    float4 v = reinterpret_cast<const float4*>(in)[i];
    reinterpret_cast<uint2*>(out)[i] = make_uint2(pk2(v.x, v.y), pk2(v.z, v.w));
  }
}

// -------- fp32 [R][C] -> bf16 [C][R] transpose via LDS tile --------
__global__ void transpose_cvt_kernel(const float* __restrict__ in, u16* __restrict__ out,
                                     int R, int C) {
  __shared__ float tile[32][33];
  int c0 = blockIdx.x * 32, r0 = blockIdx.y * 32;
  int tx = threadIdx.x, ty = threadIdx.y;
#pragma unroll
  for (int i = 0; i < 32; i += 8)
    tile[ty + i][tx] = in[(size_t)(r0 + ty + i) * C + c0 + tx];
  __syncthreads();
#pragma unroll
  for (int i = 0; i < 32; i += 8)
    out[(size_t)(c0 + ty + i) * R + r0 + tx] = f2bf(tile[tx][ty + i]);
}

// ---------------- bf16 GEMM: C = A[M,K] * Bt[N,K]^T + bias ----------------
// global_load_lds(16B) staging, LINEAR LDS (m97 structure).
// EPI==0: scatter to Q/K head-split [bh][s][d] (Q pre-scaled by 0.125) and
//         V transposed [bh][d][s] (bf16)
// EPI==1: plain fp32 [M][N] output
template <int EPI>
__global__ __launch_bounds__(256, 2) void gemm_bt_kernel(
    const u16* __restrict__ A, const u16* __restrict__ Bt,
    const float* __restrict__ bias, float* __restrict__ Cout,
    u16* __restrict__ Qo, u16* __restrict__ Ko, u16* __restrict__ Vto,
    int M, int N, int K) {
  __shared__ __align__(16) char lds[32768];
  char* As = lds;            // 128 rows x 64 bf16, linear 128B rows
  char* Bs = lds + 16384;
  int tid = threadIdx.x;
  int lane = tid & 63, l15 = lane & 15, l4 = lane >> 4;
  int w = tid >> 6, wr = w >> 1, wc = w & 1;
  int m0 = blockIdx.y * 128, n0 = blockIdx.x * 128;
  int srow = tid >> 3, sch = tid & 7;

  const u16* Ap = A + (size_t)(m0 + srow) * K + sch * 8;
  const u16* Bp = Bt + (size_t)(n0 + srow) * K + sch * 8;

  f32x4 acc[4][4] = {};

  for (int k0 = 0; k0 < K; k0 += 64) {
    __syncthreads();
#pragma unroll
    for (int i = 0; i < 4; i++) {
      gload_lds16(Ap + (size_t)i * 32 * K + k0, As + i * 4096 + tid * 16);
      gload_lds16(Bp + (size_t)i * 32 * K + k0, Bs + i * 4096 + tid * 16);
    }
    __syncthreads();
#pragma unroll
    for (int ks = 0; ks < 2; ks++) {
      int ch = ks * 4 + l4;
      bf16x8 af[4], bfv[4];
#pragma unroll
      for (int mi = 0; mi < 4; mi++)
        af[mi] = *reinterpret_cast<const bf16x8*>(As + (wr * 64 + mi * 16 + l15) * 128 + ch * 16);
#pragma unroll
      for (int nj = 0; nj < 4; nj++)
        bfv[nj] = *reinterpret_cast<const bf16x8*>(Bs + (wc * 64 + nj * 16 + l15) * 128 + ch * 16);
#pragma unroll
      for (int mi = 0; mi < 4; mi++)
#pragma unroll
        for (int nj = 0; nj < 4; nj++)
          acc[mi][nj] = __builtin_amdgcn_mfma_f32_16x16x32_bf16(af[mi], bfv[nj], acc[mi][nj], 0, 0, 0);
    }
  }

#pragma unroll
  for (int nj = 0; nj < 4; nj++) {
    int n = n0 + wc * 64 + nj * 16 + l15;
    float bv = bias[n];
#pragma unroll
    for (int mi = 0; mi < 4; mi++) {
#pragma unroll
      for (int r = 0; r < 4; r++) {
        int m = m0 + wr * 64 + mi * 16 + l4 * 4 + r;
        float v = acc[mi][nj][r] + bv;
        if (EPI == 1) {
          Cout[(size_t)m * N + n] = v;
        } else {
          int b = m >> 11, s = m & 2047;
          int sec = n >> 10, c = n & 1023, h = c >> 6, d = c & 63;
          size_t bh = (size_t)(b * NH + h);
          if (sec == 0)      Qo[(bh * SEQ + s) * HD + d] = f2bf(v * 0.125f);  // fold softmax scale
          else if (sec == 1) Ko[(bh * SEQ + s) * HD + d] = f2bf(v);
          else               Vto[(bh * HD + d) * SEQ + s] = f2bf(v);
        }
      }
    }
  }
}

// ---------------- causal flash attention, balanced pairs ----------------
// 512 blocks x 128 threads (2 waves x 32 q-rows = one 64-row q-tile).
// Each block does q-tiles (31-pair) then (pair): exactly 33 KV steps.
// S^T/O^T swapped MFMA structure: lane&15 = q -> softmax is lane-local,
// P-writes are ds_write_b64, O epilogue is packed 8B stores.
// KV tiles double-buffered via global_load_lds with pre-swizzled source;
// one vmcnt(0)+barrier per step; stage stream continues across passes.
__global__ __launch_bounds__(128) void attn_kernel(
    const u16* __restrict__ Q, const u16* __restrict__ K,
    const u16* __restrict__ Vt, u16* __restrict__ O) {
  __shared__ __align__(16) char lds[40960];  // K 2x8KB | V 2x8KB | P 2x4KB
  int tid = threadIdx.x, lane = tid & 63, w = tid >> 6;
  int l15 = lane & 15, l4 = lane >> 4;
  // XCD-clustered decode: xcd = blk&7 owns 4 bh entirely (KV 2MB -> L2-fit)
  int blk = blockIdx.x;
  int xcd = blk & 7, idx = blk >> 3;
  int bh = xcd * 4 + (idx >> 4);
  int pairIdx = idx & 15;
  const u16* Qh = Q + (size_t)bh * SEQ * HD;
  const u16* Kh = K + (size_t)bh * SEQ * HD;
  const u16* Vh = Vt + (size_t)bh * HD * SEQ;
  char* Pw = lds + 32768 + w * 4096;
  int srow = tid >> 3, sch = tid & 7;
  int b_ = bh >> 4, h_ = bh & 15;

  auto stageKV = [&](int b, int kt) {
    char* Kb = lds + b * 8192;
    char* Vb = lds + 16384 + b * 8192;
    const u16* Kt = Kh + (size_t)kt * 64 * HD;
    const u16* Vs = Vh + (size_t)kt * 64;
#pragma unroll
    for (int i = 0; i < 4; i++) {
      int row = i * 16 + srow;
      int c = (sch ^ (row & 7)) << 3;  // pre-swizzled source chunk (u16 units)
      gload_lds16(Kt + (size_t)row * HD + c, Kb + i * 2048 + tid * 16);
      gload_lds16(Vs + (size_t)row * SEQ + c, Vb + i * 2048 + tid * 16);
    }
  };

  int buf = 0;
  stageKV(0, 0);
  asm volatile("s_waitcnt vmcnt(0)" ::: "memory");
  __syncthreads();

  for (int pass = 0; pass < 2; pass++) {
    int qt = (pass == 0) ? (31 - pairIdx) : pairIdx;
    int nkt = qt + 1;
    int qbase = qt * 64 + w * 32;

    // Q fragments (pre-scaled by 0.125): B-operand, lane&15 = q-row
    bf16x8 qf[2][2];
#pragma unroll
    for (int mi = 0; mi < 2; mi++)
#pragma unroll
      for (int ks = 0; ks < 2; ks++)
        qf[mi][ks] = *reinterpret_cast<const bf16x8*>(
            Qh + (size_t)(qbase + mi * 16 + l15) * HD + ks * 32 + l4 * 8);

    float mrun[2] = {-1e30f, -1e30f}, lrun[2] = {0.0f, 0.0f};
    f32x4 oacc[4][2] = {};

    for (int kt = 0; kt < nkt; kt++) {
      int nxt = (kt + 1 < nkt) ? (kt + 1) : (pass == 0 ? 0 : -1);
      if (nxt >= 0) stageKV(buf ^ 1, nxt);

      char* Kb = lds + buf * 8192;
      char* Vb = lds + 16384 + buf * 8192;

      // S^T = K · Q^T   (D: row = kv = l4*4+r, col = q = l15)
      f32x4 s[4][2] = {};
#pragma unroll
      for (int ks = 0; ks < 2; ks++)
#pragma unroll
        for (int nj = 0; nj < 4; nj++) {
          bf16x8 kf = *reinterpret_cast<const bf16x8*>(Kb + swz128(nj * 16 + l15, ks * 4 + l4));
#pragma unroll
          for (int mi = 0; mi < 2; mi++)
            s[nj][mi] = __builtin_amdgcn_mfma_f32_16x16x32_bf16(kf, qf[mi][ks], s[nj][mi], 0, 0, 0);
        }

      // causal mask: only the diagonal tile needs it
      if (kt == qt) {
        int ktb = kt * 64;
#pragma unroll
        for (int nj = 0; nj < 4; nj++)
#pragma unroll
          for (int mi = 0; mi < 2; mi++) {
            int qg = qbase + mi * 16 + l15;
#pragma unroll
            for (int r = 0; r < 4; r++) {
              int kg = ktb + nj * 16 + l4 * 4 + r;
              if (kg > qg) s[nj][mi][r] = MVAL;
            }
          }
      }

      // online softmax: q is lane-local (l15), reduce across l4 (2 shuffles)
      float alpha[2];
#pragma unroll
      for (int mi = 0; mi < 2; mi++) {
        float mt = s[0][mi][0];
#pragma unroll
        for (int nj = 0; nj < 4; nj++)
#pragma unroll
          for (int r = 0; r < 4; r++) mt = fmaxf(mt, s[nj][mi][r]);
        mt = fmaxf(mt, __shfl_xor(mt, 16));
        mt = fmaxf(mt, __shfl_xor(mt, 32));
        float mnew = fmaxf(mrun[mi], mt);
        alpha[mi] = __expf(mrun[mi] - mnew);
        mrun[mi] = mnew;
        float rs = 0.0f;
        int prow = mi * 16 + l15;
#pragma unroll
        for (int nj = 0; nj < 4; nj++) {
          float p0 = __expf(s[nj][mi][0] - mnew);
          float p1 = __expf(s[nj][mi][1] - mnew);
          float p2 = __expf(s[nj][mi][2] - mnew);
          float p3 = __expf(s[nj][mi][3] - mnew);
          rs += (p0 + p1) + (p2 + p3);
          int chunk = nj * 2 + (l4 >> 1);
          char* dst = Pw + prow * 128 + (((chunk ^ (prow & 7)) & 7) << 4) + (l4 & 1) * 8;
          *reinterpret_cast<uint2*>(dst) = make_uint2(pk2(p0, p1), pk2(p2, p3));
        }
        rs += __shfl_xor(rs, 16);
        rs += __shfl_xor(rs, 32);
        lrun[mi] = lrun[mi] * alpha[mi] + rs;
      }
#pragma unroll
      for (int nd = 0; nd < 4; nd++)
#pragma unroll
        for (int mi = 0; mi < 2; mi++)
#pragma unroll
          for (int r = 0; r < 4; r++) oacc[nd][mi][r] *= alpha[mi];

      asm volatile("s_waitcnt lgkmcnt(0)" ::: "memory");
      __builtin_amdgcn_sched_barrier(0);

      // P fragments: B-operand from Pw[q][kv]
      bf16x8 pf[2][2];
#pragma unroll
      for (int mi = 0; mi < 2; mi++)
#pragma unroll
        for (int ks = 0; ks < 2; ks++)
          pf[mi][ks] = *reinterpret_cast<const bf16x8*>(Pw + swz128(mi * 16 + l15, ks * 4 + l4));

      // O^T += V^T · P^T   (D: row = d = l4*4+r, col = q = l15)
#pragma unroll
      for (int ks = 0; ks < 2; ks++)
#pragma unroll
        for (int nd = 0; nd < 4; nd++) {
          bf16x8 vf = *reinterpret_cast<const bf16x8*>(Vb + swz128(nd * 16 + l15, ks * 4 + l4));
#pragma unroll
          for (int mi = 0; mi < 2; mi++)
            oacc[nd][mi] = __builtin_amdgcn_mfma_f32_16x16x32_bf16(vf, pf[mi][ks], oacc[nd][mi], 0, 0, 0);
        }

      asm volatile("s_waitcnt vmcnt(0)" ::: "memory");
      __syncthreads();
      buf ^= 1;
    }

    // epilogue: O^T lane holds 4 consecutive d for q = l15 -> packed 8B stores
#pragma unroll
    for (int mi = 0; mi < 2; mi++) {
      float inv = 1.0f / lrun[mi];
      int sg = qbase + mi * 16 + l15;
      u16* orow = O + ((size_t)b_ * SEQ + sg) * DIM + h_ * HD;
#pragma unroll
      for (int nd = 0; nd < 4; nd++) {
        uint32_t lo = pk2(oacc[nd][mi][0] * inv, oacc[nd][mi][1] * inv);
        uint32_t hi = pk2(oacc[nd][mi][2] * inv, oacc[nd][mi][3] * inv);
        *reinterpret_cast<uint2*>(orow + nd * 16 + l4 * 4) = make_uint2(lo, hi);
      }
    }
  }
}

extern "C" void kernel_launch(void* const* d_in, const int* in_sizes, int n_in,
                              void* d_out, int out_size, void* d_ws, size_t ws_size,
                              hipStream_t stream) {
  const float* x     = (const float*)d_in[0];
  const float* W_qkv = (const float*)d_in[1];
  const float* b_qkv = (const float*)d_in[2];
  const float* W_out = (const float*)d_in[3];
  const float* b_out = (const float*)d_in[4];
  float* out = (float*)d_out;
  char* ws = (char*)d_ws;

  // ws layout (bytes)
  u16* xb    = (u16*)(ws);                               // 8 MB  [4096][1024]
  u16* WqkvT = (u16*)(ws + 8388608);                     // 6 MB  [3072][1024]
  u16* WoutT = (u16*)(ws + 8388608 + 6291456);           // 2 MB  [1024][1024]
  u16* Qb    = (u16*)(ws + 16777216);                    // 8 MB  [32][2048][64]
  u16* Kb    = (u16*)(ws + 16777216 + 8388608);          // 8 MB  [32][2048][64]
  u16* Vtb   = (u16*)(ws + 16777216 + 2 * 8388608);      // 8 MB  [32][64][2048]
  u16* Ob    = (u16*)(ws + 16777216 + 3 * 8388608);      // 8 MB  [4096][1024]

  cvt_kernel<<<4096, 256, 0, stream>>>(x, xb, BATCH * SEQ * DIM / 4);
  transpose_cvt_kernel<<<dim3(3 * DIM / 32, DIM / 32), dim3(32, 8), 0, stream>>>(
      W_qkv, WqkvT, DIM, 3 * DIM);
  transpose_cvt_kernel<<<dim3(DIM / 32, DIM / 32), dim3(32, 8), 0, stream>>>(
      W_out, WoutT, DIM, DIM);
  gemm_bt_kernel<0><<<dim3(3 * DIM / 128, BATCH * SEQ / 128), 256, 0, stream>>>(
      xb, WqkvT, b_qkv, nullptr, Qb, Kb, Vtb, BATCH * SEQ, 3 * DIM, DIM);
  attn_kernel<<<512, 128, 0, stream>>>(Qb, Kb, Vtb, Ob);
  gemm_bt_kernel<1><<<dim3(DIM / 128, BATCH * SEQ / 128), 256, 0, stream>>>(
      Ob, WoutT, b_out, out, nullptr, nullptr, nullptr, BATCH * SEQ, DIM, DIM);
}

// Round 4
// 125.544 us; speedup vs baseline: 1.8389x; 1.1932x over previous
//
#include <hip/hip_runtime.h>
#include <hip/hip_bf16.h>
#include <stdint.h>

#define BATCH 2
#define SEQ   2048
#define DIM   1024
#define NH    16
#define HD    64
#define MVAL  (-10000.0f)

typedef __attribute__((ext_vector_type(8))) short bf16x8;
typedef __attribute__((ext_vector_type(4))) float f32x4;
typedef unsigned short u16;

static __device__ __forceinline__ u16 f2bf(float f) {
  union { float f; uint32_t u; } c; c.f = f;
  uint32_t x = c.u;
  return (u16)((x + 0x7fffu + ((x >> 16) & 1u)) >> 16);  // RNE
}

static __device__ __forceinline__ uint32_t pk2(float a, float b) {
  __hip_bfloat162 h = __float22bfloat162_rn(make_float2(a, b));
  union { __hip_bfloat162 h; uint32_t u; } c; c.h = h;
  return c.u;
}

// swizzled byte offset within LDS tiles of 128B rows (8 x 16B chunks)
static __device__ __forceinline__ int swz128(int row, int chunk) {
  return row * 128 + (((chunk ^ (row & 7)) & 7) << 4);
}

static __device__ __forceinline__ void gload_lds16(const void* g, void* l) {
  __builtin_amdgcn_global_load_lds((const __attribute__((address_space(1))) void*)g,
                                   (__attribute__((address_space(3))) void*)l, 16, 0, 0);
}

// ---------------- fp32 -> bf16 convert (vectorized) ----------------
__global__ void cvt_kernel(const float* __restrict__ in, u16* __restrict__ out, int n4) {
  int i = blockIdx.x * blockDim.x + threadIdx.x;
  if (i < n4) {
    float4 v = reinterpret_cast<const float4*>(in)[i];
    reinterpret_cast<uint2*>(out)[i] = make_uint2(pk2(v.x, v.y), pk2(v.z, v.w));
  }
}

// -------- fp32 [R][C] -> bf16 [C][R] transpose via LDS tile --------
__global__ void transpose_cvt_kernel(const float* __restrict__ in, u16* __restrict__ out,
                                     int R, int C) {
  __shared__ float tile[32][33];
  int c0 = blockIdx.x * 32, r0 = blockIdx.y * 32;
  int tx = threadIdx.x, ty = threadIdx.y;
#pragma unroll
  for (int i = 0; i < 32; i += 8)
    tile[ty + i][tx] = in[(size_t)(r0 + ty + i) * C + c0 + tx];
  __syncthreads();
#pragma unroll
  for (int i = 0; i < 32; i += 8)
    out[(size_t)(c0 + ty + i) * R + r0 + tx] = f2bf(tile[tx][ty + i]);
}

// ---------------- bf16 GEMM: C = A[M,K] * Bt[N,K]^T + bias ----------------
template <int EPI>
__global__ __launch_bounds__(256, 2) void gemm_bt_kernel(
    const u16* __restrict__ A, const u16* __restrict__ Bt,
    const float* __restrict__ bias, float* __restrict__ Cout,
    u16* __restrict__ Qo, u16* __restrict__ Ko, u16* __restrict__ Vto,
    int M, int N, int K) {
  __shared__ __align__(16) char lds[32768];
  char* As = lds;            // 128 rows x 64 bf16, linear 128B rows
  char* Bs = lds + 16384;
  int tid = threadIdx.x;
  int lane = tid & 63, l15 = lane & 15, l4 = lane >> 4;
  int w = tid >> 6, wr = w >> 1, wc = w & 1;
  int m0 = blockIdx.y * 128, n0 = blockIdx.x * 128;
  int srow = tid >> 3, sch = tid & 7;

  const u16* Ap = A + (size_t)(m0 + srow) * K + sch * 8;
  const u16* Bp = Bt + (size_t)(n0 + srow) * K + sch * 8;

  f32x4 acc[4][4] = {};

  for (int k0 = 0; k0 < K; k0 += 64) {
    __syncthreads();
#pragma unroll
    for (int i = 0; i < 4; i++) {
      gload_lds16(Ap + (size_t)i * 32 * K + k0, As + i * 4096 + tid * 16);
      gload_lds16(Bp + (size_t)i * 32 * K + k0, Bs + i * 4096 + tid * 16);
    }
    __syncthreads();
#pragma unroll
    for (int ks = 0; ks < 2; ks++) {
      int ch = ks * 4 + l4;
      bf16x8 af[4], bfv[4];
#pragma unroll
      for (int mi = 0; mi < 4; mi++)
        af[mi] = *reinterpret_cast<const bf16x8*>(As + (wr * 64 + mi * 16 + l15) * 128 + ch * 16);
#pragma unroll
      for (int nj = 0; nj < 4; nj++)
        bfv[nj] = *reinterpret_cast<const bf16x8*>(Bs + (wc * 64 + nj * 16 + l15) * 128 + ch * 16);
#pragma unroll
      for (int mi = 0; mi < 4; mi++)
#pragma unroll
        for (int nj = 0; nj < 4; nj++)
          acc[mi][nj] = __builtin_amdgcn_mfma_f32_16x16x32_bf16(af[mi], bfv[nj], acc[mi][nj], 0, 0, 0);
    }
  }

#pragma unroll
  for (int nj = 0; nj < 4; nj++) {
    int n = n0 + wc * 64 + nj * 16 + l15;
    float bv = bias[n];
#pragma unroll
    for (int mi = 0; mi < 4; mi++) {
#pragma unroll
      for (int r = 0; r < 4; r++) {
        int m = m0 + wr * 64 + mi * 16 + l4 * 4 + r;
        float v = acc[mi][nj][r] + bv;
        if (EPI == 1) {
          Cout[(size_t)m * N + n] = v;
        } else {
          int b = m >> 11, s = m & 2047;
          int sec = n >> 10, c = n & 1023, h = c >> 6, d = c & 63;
          size_t bh = (size_t)(b * NH + h);
          if (sec == 0)      Qo[(bh * SEQ + s) * HD + d] = f2bf(v * 0.125f);  // fold softmax scale
          else if (sec == 1) Ko[(bh * SEQ + s) * HD + d] = f2bf(v);
          else               Vto[(bh * HD + d) * SEQ + s] = f2bf(v);
        }
      }
    }
  }
}

// ---------------- causal flash attention: 4 waves, kv-parity split ----------------
// 512 blocks x 256 threads. Block = (bh, pair p): q-tiles (31-p) then (p), 64 rows each.
// Waves: sub = w&1 (q-row half, 32 rows), par = w>>1 (kv 64-half of each 128-wide tile).
// Every block runs exactly 17 double-width KV steps -> perfectly balanced; 2 blocks/CU
// (80KB LDS) -> 8 waves/CU = 2/SIMD TLP. Per-pass cross-parity merge through the DEAD
// K double-buffer (fp32 exact). Swapped MFMA (lane&15 = q) throughout.
__global__ __launch_bounds__(256, 2) void attn_kernel(
    const u16* __restrict__ Q, const u16* __restrict__ K,
    const u16* __restrict__ Vt, u16* __restrict__ O) {
  __shared__ __align__(16) char lds[81920];  // K 2x16KB | V 2x16KB | P 4x4KB
  int tid = threadIdx.x, lane = tid & 63, w = tid >> 6;
  int l15 = lane & 15, l4 = lane >> 4;
  int sub = w & 1, par = w >> 1;
  int blk = blockIdx.x;
  // XCD-clustered: xcd = blk&7 sees bh in {4*xcd .. 4*xcd+3}
  int bh = (blk & 7) * 4 + ((blk >> 3) & 3);
  int p = blk >> 5;
  const u16* Qh = Q + (size_t)bh * SEQ * HD;
  const u16* Kh = K + (size_t)bh * SEQ * HD;
  const u16* Vh = Vt + (size_t)bh * HD * SEQ;
  char* Pw = lds + 65536 + w * 4096;
  int srow = tid >> 3, sch = tid & 7;
  int b_ = bh >> 4, h_ = bh & 15;

  // stage one 128-wide KV tile: K as 2x[64][64] subtiles, V^T as 2x[64][64] subtiles
  auto stageKV = [&](int b, int T) {
    const u16* Kt = Kh + (size_t)T * 128 * HD;
    const u16* Vs = Vh + (size_t)T * 128;
    char* Kb = lds + b * 16384;
    char* Vb = lds + 32768 + b * 16384;
#pragma unroll
    for (int i = 0; i < 4; i++) {
      int row = i * 32 + srow;
      int c = (sch ^ (row & 7)) << 3;  // pre-swizzled source (u16 units)
      gload_lds16(Kt + (size_t)row * HD + c, Kb + row * 128 + sch * 16);
    }
#pragma unroll
    for (int sv = 0; sv < 2; sv++)
#pragma unroll
      for (int i = 0; i < 2; i++) {
        int d = i * 32 + srow;
        int c = (sch ^ (d & 7)) << 3;
        gload_lds16(Vs + (size_t)d * SEQ + sv * 64 + c, Vb + sv * 8192 + d * 128 + sch * 16);
      }
  };

  int buf = 0;
  stageKV(0, 0);
  __syncthreads();  // drains vmcnt

  for (int pass = 0; pass < 2; pass++) {
    int qt = (pass == 0) ? (31 - p) : p;
    int nT = (qt + 2) >> 1;          // 128-wide tiles covering kv [0, (qt+1)*64)
    int qb = qt * 64 + sub * 32;     // this wave's 32 q-rows

    // Q fragments (pre-scaled by 0.125): B-operand, lane&15 = q-row
    bf16x8 qf[2][2];
#pragma unroll
    for (int mi = 0; mi < 2; mi++)
#pragma unroll
      for (int ks = 0; ks < 2; ks++)
        qf[mi][ks] = *reinterpret_cast<const bf16x8*>(
            Qh + (size_t)(qb + mi * 16 + l15) * HD + ks * 32 + l4 * 8);

    float mrun[2] = {-1e30f, -1e30f}, lrun[2] = {0.0f, 0.0f};
    f32x4 oacc[4][2] = {};

    for (int T = 0; T < nT; T++) {
      int nxt = (T + 1 < nT) ? (T + 1) : (pass == 0 ? 0 : -1);
      if (nxt >= 0) stageKV(buf ^ 1, nxt);

      char* Kw = lds + buf * 16384 + par * 8192;
      char* Vw = lds + 32768 + buf * 16384 + par * 8192;
      int kvb = T * 128 + par * 64;

      // S^T = K · Q^T   (D: row = kv = l4*4+r, col = q = l15)
      f32x4 s[4][2] = {};
      __builtin_amdgcn_s_setprio(1);
#pragma unroll
      for (int ks = 0; ks < 2; ks++)
#pragma unroll
        for (int nj = 0; nj < 4; nj++) {
          bf16x8 kf = *reinterpret_cast<const bf16x8*>(Kw + swz128(nj * 16 + l15, ks * 4 + l4));
#pragma unroll
          for (int mi = 0; mi < 2; mi++)
            s[nj][mi] = __builtin_amdgcn_mfma_f32_16x16x32_bf16(kf, qf[mi][ks], s[nj][mi], 0, 0, 0);
        }
      __builtin_amdgcn_s_setprio(0);

      // causal mask: only tiles that touch/exceed the diagonal
      if (kvb + 63 > qb) {
#pragma unroll
        for (int nj = 0; nj < 4; nj++)
#pragma unroll
          for (int mi = 0; mi < 2; mi++) {
            int qg = qb + mi * 16 + l15;
#pragma unroll
            for (int r = 0; r < 4; r++) {
              int kg = kvb + nj * 16 + l4 * 4 + r;
              if (kg > qg) s[nj][mi][r] = MVAL;
            }
          }
      }

      // online softmax: q lane-local (l15), reduce across l4 (2 shuffles)
      float alpha[2];
#pragma unroll
      for (int mi = 0; mi < 2; mi++) {
        float mt = s[0][mi][0];
#pragma unroll
        for (int nj = 0; nj < 4; nj++)
#pragma unroll
          for (int r = 0; r < 4; r++) mt = fmaxf(mt, s[nj][mi][r]);
        mt = fmaxf(mt, __shfl_xor(mt, 16));
        mt = fmaxf(mt, __shfl_xor(mt, 32));
        float mnew = fmaxf(mrun[mi], mt);
        alpha[mi] = __expf(mrun[mi] - mnew);
        mrun[mi] = mnew;
        float rs = 0.0f;
        int prow = mi * 16 + l15;
#pragma unroll
        for (int nj = 0; nj < 4; nj++) {
          float p0 = __expf(s[nj][mi][0] - mnew);
          float p1 = __expf(s[nj][mi][1] - mnew);
          float p2 = __expf(s[nj][mi][2] - mnew);
          float p3 = __expf(s[nj][mi][3] - mnew);
          rs += (p0 + p1) + (p2 + p3);
          int chunk = nj * 2 + (l4 >> 1);
          char* dst = Pw + prow * 128 + (((chunk ^ (prow & 7)) & 7) << 4) + (l4 & 1) * 8;
          *reinterpret_cast<uint2*>(dst) = make_uint2(pk2(p0, p1), pk2(p2, p3));
        }
        rs += __shfl_xor(rs, 16);
        rs += __shfl_xor(rs, 32);
        lrun[mi] = lrun[mi] * alpha[mi] + rs;
      }
#pragma unroll
      for (int nd = 0; nd < 4; nd++)
#pragma unroll
        for (int mi = 0; mi < 2; mi++)
#pragma unroll
          for (int r = 0; r < 4; r++) oacc[nd][mi][r] *= alpha[mi];

      asm volatile("s_waitcnt lgkmcnt(0)" ::: "memory");
      __builtin_amdgcn_sched_barrier(0);

      // P fragments: B-operand from Pw[q][kv]
      bf16x8 pf[2][2];
#pragma unroll
      for (int mi = 0; mi < 2; mi++)
#pragma unroll
        for (int ks = 0; ks < 2; ks++)
          pf[mi][ks] = *reinterpret_cast<const bf16x8*>(Pw + swz128(mi * 16 + l15, ks * 4 + l4));

      // O^T += V^T · P^T   (D: row = d = l4*4+r, col = q = l15)
      __builtin_amdgcn_s_setprio(1);
#pragma unroll
      for (int ks = 0; ks < 2; ks++)
#pragma unroll
        for (int nd = 0; nd < 4; nd++) {
          bf16x8 vf = *reinterpret_cast<const bf16x8*>(Vw + swz128(nd * 16 + l15, ks * 4 + l4));
#pragma unroll
          for (int mi = 0; mi < 2; mi++)
            oacc[nd][mi] = __builtin_amdgcn_mfma_f32_16x16x32_bf16(vf, pf[mi][ks], oacc[nd][mi], 0, 0, 0);
        }
      __builtin_amdgcn_s_setprio(0);

      __syncthreads();  // drains vmcnt (next tile staged) + lgkm; all waves step together
      buf ^= 1;
    }

    // ---- cross-parity merge through the dead K buffer (fp32 exact) ----
    char* Xo = lds + (buf ^ 1) * 16384;       // 64 rows x 256B fp32
    float* Xml = (float*)(lds + 65536);       // 64 x (m,l) in dead P region
    if (par == 1) {
#pragma unroll
      for (int mi = 0; mi < 2; mi++) {
        int row = sub * 32 + mi * 16 + l15;
        if (l4 == 0) {
          Xml[row * 2] = mrun[mi];
          Xml[row * 2 + 1] = lrun[mi];
        }
#pragma unroll
        for (int nd = 0; nd < 4; nd++)
          *reinterpret_cast<f32x4*>(Xo + row * 256 + (((nd * 4 + l4) ^ (row & 7)) << 4)) =
              oacc[nd][mi];
      }
    }
    __syncthreads();
    if (par == 0) {
#pragma unroll
      for (int mi = 0; mi < 2; mi++) {
        int row = sub * 32 + mi * 16 + l15;
        float mB = Xml[row * 2], lB = Xml[row * 2 + 1];
        float m = fmaxf(mrun[mi], mB);
        float wA = __expf(mrun[mi] - m), wB = __expf(mB - m);
        float linv = 1.0f / (lrun[mi] * wA + lB * wB);
        u16* orow = O + ((size_t)b_ * SEQ + qt * 64 + sub * 32 + mi * 16 + l15) * DIM + h_ * HD;
#pragma unroll
        for (int nd = 0; nd < 4; nd++) {
          f32x4 ob = *reinterpret_cast<const f32x4*>(
              Xo + row * 256 + (((nd * 4 + l4) ^ (row & 7)) << 4));
          float o0 = (oacc[nd][mi][0] * wA + ob[0] * wB) * linv;
          float o1 = (oacc[nd][mi][1] * wA + ob[1] * wB) * linv;
          float o2 = (oacc[nd][mi][2] * wA + ob[2] * wB) * linv;
          float o3 = (oacc[nd][mi][3] * wA + ob[3] * wB) * linv;
          *reinterpret_cast<uint2*>(orow + nd * 16 + l4 * 4) = make_uint2(pk2(o0, o1), pk2(o2, o3));
        }
      }
    }
    __syncthreads();  // protect Xo/Xml before next pass's staging overwrites
  }
}

extern "C" void kernel_launch(void* const* d_in, const int* in_sizes, int n_in,
                              void* d_out, int out_size, void* d_ws, size_t ws_size,
                              hipStream_t stream) {
  const float* x     = (const float*)d_in[0];
  const float* W_qkv = (const float*)d_in[1];
  const float* b_qkv = (const float*)d_in[2];
  const float* W_out = (const float*)d_in[3];
  const float* b_out = (const float*)d_in[4];
  float* out = (float*)d_out;
  char* ws = (char*)d_ws;

  // ws layout (bytes)
  u16* xb    = (u16*)(ws);                               // 8 MB  [4096][1024]
  u16* WqkvT = (u16*)(ws + 8388608);                     // 6 MB  [3072][1024]
  u16* WoutT = (u16*)(ws + 8388608 + 6291456);           // 2 MB  [1024][1024]
  u16* Qb    = (u16*)(ws + 16777216);                    // 8 MB  [32][2048][64]
  u16* Kb    = (u16*)(ws + 16777216 + 8388608);          // 8 MB  [32][2048][64]
  u16* Vtb   = (u16*)(ws + 16777216 + 2 * 8388608);      // 8 MB  [32][64][2048]
  u16* Ob    = (u16*)(ws + 16777216 + 3 * 8388608);      // 8 MB  [4096][1024]

  cvt_kernel<<<4096, 256, 0, stream>>>(x, xb, BATCH * SEQ * DIM / 4);
  transpose_cvt_kernel<<<dim3(3 * DIM / 32, DIM / 32), dim3(32, 8), 0, stream>>>(
      W_qkv, WqkvT, DIM, 3 * DIM);
  transpose_cvt_kernel<<<dim3(DIM / 32, DIM / 32), dim3(32, 8), 0, stream>>>(
      W_out, WoutT, DIM, DIM);
  gemm_bt_kernel<0><<<dim3(3 * DIM / 128, BATCH * SEQ / 128), 256, 0, stream>>>(
      xb, WqkvT, b_qkv, nullptr, Qb, Kb, Vtb, BATCH * SEQ, 3 * DIM, DIM);
  attn_kernel<<<512, 256, 0, stream>>>(Qb, Kb, Vtb, Ob);
  gemm_bt_kernel<1><<<dim3(DIM / 128, BATCH * SEQ / 128), 256, 0, stream>>>(
      Ob, WoutT, b_out, out, nullptr, nullptr, nullptr, BATCH * SEQ, DIM, DIM);
}